// Round 5
// baseline (1218.869 us; speedup 1.0000x reference)
//
#include <hip/hip_runtime.h>

// Attractor: hs <- normalize(leaky_relu(0.5*hs + hs@M)), TAU=16, B=8, D=8192 (fp32 I/O).
//
// R4 post-mortem: removing per-step normalization fails in fp32 — rows that
// converge to the NEGATIVE uniform fixed point shrink by ~0.01/step (leaky
// slope), hit 1e-34 by step 16, and their squares flush to zero in the final
// sumsq -> output rows become 0 (absmax == max|ref|). Per-step normalize is
// required for range, so it is fused into the combine kernel (R2's proven
// pattern).
//
// matmul: grid (64 col-strips x 16 k-slices), 256 thr, launch_bounds(256,4).
//   Block: 128 cols x 512 k. Thread: 4 cols x 64 k. h-tile transposed in LDS
//   (lds[k*12+r]); M streamed as ushort4 bf16 (16 loads in flight); in-block
//   LDS reduce over 8 k-subslices -> part[16][8][8192] (4 MiB). Step 0 reads
//   fp32 M and emits bf16 M as a byproduct (fused convert).
// combine_norm: 8 blocks (1 row) x 1024 thr. s = sum_16 part + 0.5*hs_prev,
//   a = leaky(s), row sumsq via wave-64 shuffle + LDS, hs = a*inv.
//   Final step also writes d_out.

#define DD 8192
#define BB 8
#define TAU 16
#define NCS 64     // column strips of 128
#define NKS 16     // k slices of 512
#define KSL 512
#define SLOPEF 0.01f
#define EPSF 1e-12f

static __device__ __forceinline__ float b2f(unsigned short u) {
    union { unsigned int i; float f; } v; v.i = ((unsigned int)u) << 16; return v.f;
}
static __device__ __forceinline__ unsigned short f2b(float f) {
    union { float f; unsigned int i; } v; v.f = f;
    unsigned int r = v.i + 0x7FFFu + ((v.i >> 16) & 1u);   // RNE
    return (unsigned short)(r >> 16);
}

template <bool FIRST>
__global__ __launch_bounds__(256, 4) void matmul_kernel(const float* __restrict__ h,
                                                        const float* __restrict__ Mf,
                                                        unsigned short* __restrict__ Mb,
                                                        float* __restrict__ part) {
    __shared__ float lds[8192];   // 32 KiB: h-tile (6144 used) then reduce scratch
    const int t  = threadIdx.x;
    const int j0 = blockIdx.x * 128;
    const int k0 = blockIdx.y * KSL;
    const int c4 = (t & 31) * 4;     // col offset within strip
    const int ss = t >> 5;           // k subslice 0..7 (64 k each)

    // stage h[0:8, k0:k0+512] transposed: lds[k*12 + r]
    {
        const int k2 = 2 * t;
#pragma unroll
        for (int r = 0; r < BB; r++) {
            const float2 v = *(const float2*)&h[r * DD + k0 + k2];
            lds[k2 * 12 + r]       = v.x;
            lds[(k2 + 1) * 12 + r] = v.y;
        }
    }
    __syncthreads();

    float4 acc[BB];
#pragma unroll
    for (int r = 0; r < BB; r++) acc[r] = make_float4(0.f, 0.f, 0.f, 0.f);

    const int kb0 = ss * 64;   // thread's local k base

    if constexpr (FIRST) {
        const float* Mp = Mf + (size_t)(k0 + kb0) * DD + j0 + c4;
        unsigned short* Mw = Mb + (size_t)(k0 + kb0) * DD + j0 + c4;
#pragma unroll
        for (int b = 0; b < 8; b++) {
            float4 mv[8];
#pragma unroll
            for (int u = 0; u < 8; u++)
                mv[u] = *(const float4*)(Mp + (size_t)(b * 8 + u) * DD);
#pragma unroll
            for (int u = 0; u < 8; u++) {
                ushort4 o;
                o.x = f2b(mv[u].x); o.y = f2b(mv[u].y);
                o.z = f2b(mv[u].z); o.w = f2b(mv[u].w);
                *(ushort4*)(Mw + (size_t)(b * 8 + u) * DD) = o;
                // bf16-round operands so step 0 matches later steps' precision class
                const float m0 = b2f(o.x), m1 = b2f(o.y), m2 = b2f(o.z), m3 = b2f(o.w);
                const float* hk = &lds[(kb0 + b * 8 + u) * 12];
                const float4 h0 = *(const float4*)hk;
                const float4 h1 = *(const float4*)(hk + 4);
                const float hr[8] = {h0.x, h0.y, h0.z, h0.w, h1.x, h1.y, h1.z, h1.w};
#pragma unroll
                for (int r = 0; r < BB; r++) {
                    acc[r].x = fmaf(hr[r], m0, acc[r].x);
                    acc[r].y = fmaf(hr[r], m1, acc[r].y);
                    acc[r].z = fmaf(hr[r], m2, acc[r].z);
                    acc[r].w = fmaf(hr[r], m3, acc[r].w);
                }
            }
        }
    } else {
        const unsigned short* Mp = Mb + (size_t)(k0 + kb0) * DD + j0 + c4;
#pragma unroll
        for (int b = 0; b < 4; b++) {
            ushort4 mv[16];
#pragma unroll
            for (int u = 0; u < 16; u++)
                mv[u] = *(const ushort4*)(Mp + (size_t)(b * 16 + u) * DD);
#pragma unroll
            for (int u = 0; u < 16; u++) {
                const float m0 = b2f(mv[u].x), m1 = b2f(mv[u].y);
                const float m2 = b2f(mv[u].z), m3 = b2f(mv[u].w);
                const float* hk = &lds[(kb0 + b * 16 + u) * 12];
                const float4 h0 = *(const float4*)hk;
                const float4 h1 = *(const float4*)(hk + 4);
                const float hr[8] = {h0.x, h0.y, h0.z, h0.w, h1.x, h1.y, h1.z, h1.w};
#pragma unroll
                for (int r = 0; r < BB; r++) {
                    acc[r].x = fmaf(hr[r], m0, acc[r].x);
                    acc[r].y = fmaf(hr[r], m1, acc[r].y);
                    acc[r].z = fmaf(hr[r], m2, acc[r].z);
                    acc[r].w = fmaf(hr[r], m3, acc[r].w);
                }
            }
        }
    }

    __syncthreads();   // done with h-tile; reuse lds for the subslice reduce
#pragma unroll
    for (int r = 0; r < BB; r++)
        *(float4*)&lds[ss * 1024 + r * 128 + c4] = acc[r];
    __syncthreads();

    const int rr = t >> 5;           // row 0..7
    const int cc = (t & 31) * 4;     // col within strip
    float4 s = make_float4(0.f, 0.f, 0.f, 0.f);
#pragma unroll
    for (int i = 0; i < 8; i++) {
        const float4 p = *(const float4*)&lds[i * 1024 + rr * 128 + cc];
        s.x += p.x; s.y += p.y; s.z += p.z; s.w += p.w;
    }
    *(float4*)&part[(size_t)blockIdx.y * (BB * DD) + rr * DD + j0 + cc] = s;
}

// One block per row. s = sum_slices part + decay*hs_prev; a = leaky(s);
// hs = a / max(||a||, eps). Final step also writes d_out.
__global__ __launch_bounds__(1024) void combine_norm_kernel(const float* __restrict__ part,
                                                            float* __restrict__ hs,
                                                            float* __restrict__ out,
                                                            int use_decay) {
    const int r = blockIdx.x, tid = threadIdx.x;
    float a[8];
    float ssq = 0.0f;
#pragma unroll
    for (int i = 0; i < 8; i++) {
        const int col = i * 1024 + tid;
        float s = 0.0f;
#pragma unroll
        for (int sl = 0; sl < NKS; sl++)
            s += part[(size_t)sl * (BB * DD) + r * DD + col];
        if (use_decay) s = fmaf(0.5f, hs[r * DD + col], s);
        s = (s >= 0.0f) ? s : SLOPEF * s;   // leaky_relu
        a[i] = s;
        ssq = fmaf(s, s, ssq);
    }

#pragma unroll
    for (int off = 32; off > 0; off >>= 1) ssq += __shfl_down(ssq, off, 64);

    __shared__ float red[16];
    __shared__ float tots;
    if ((tid & 63) == 0) red[tid >> 6] = ssq;
    __syncthreads();
    if (tid == 0) {
        float t = 0.0f;
#pragma unroll
        for (int i = 0; i < 16; i++) t += red[i];
        tots = t;
    }
    __syncthreads();

    const float inv = 1.0f / fmaxf(sqrtf(tots), EPSF);
#pragma unroll
    for (int i = 0; i < 8; i++) {
        const int col = i * 1024 + tid;
        const float v = a[i] * inv;
        hs[r * DD + col] = v;
        if (out) out[r * DD + col] = v;
    }
}

extern "C" void kernel_launch(void* const* d_in, const int* in_sizes, int n_in,
                              void* d_out, int out_size, void* d_ws, size_t ws_size,
                              hipStream_t stream) {
    const float* x = (const float*)d_in[0];   // (8, 8192)
    const float* M = (const float*)d_in[1];   // (8192, 8192)

    unsigned short* Mbf = (unsigned short*)d_ws;                       // 128 MiB
    float* part = (float*)((char*)d_ws + (size_t)DD * DD * 2);         // 4 MiB
    float* hs   = part + (size_t)NKS * BB * DD;                        // 256 KiB

    // step 0: h = x, fp32 M (writes bf16 M), no decay
    matmul_kernel<true><<<dim3(NCS, NKS), 256, 0, stream>>>(x, M, Mbf, part);
    combine_norm_kernel<<<BB, 1024, 0, stream>>>(part, hs, nullptr, 0);

    for (int t = 1; t < TAU; t++) {
        matmul_kernel<false><<<dim3(NCS, NKS), 256, 0, stream>>>(hs, nullptr, Mbf, part);
        combine_norm_kernel<<<BB, 1024, 0, stream>>>(part, hs,
                                                     (t == TAU - 1) ? (float*)d_out : nullptr, 1);
    }
}